// Round 4
// baseline (349.684 us; speedup 1.0000x reference)
//
#include <hip/hip_runtime.h>

// EmbeddingBag(mean): V=1e6, D=64, B=16384, L=50.
// R4 layout: one wave per bag, ONE float per lane (lane = column 0..63).
// The bag's <=64 indices arrive in one coalesced load (lane l holds index l),
// then each of the `count` iterations broadcasts index j to all lanes via
// __shfl with a wave-uniform source lane (-> v_readlane, scalar row base).
// All `count` row loads (4 B/lane, 256 B/row, perfectly coalesced) are
// mutually independent -> up to 50 outstanding vmem ops per wave.
// No divergent guards in the loop, no cross-lane reduction, direct store.

__global__ __launch_bounds__(256) void FreqAwareEmbedding_kernel(
    const int* __restrict__ indices,   // [T]
    const int* __restrict__ offsets,   // [B]
    const float* __restrict__ weight,  // [V*64]
    float* __restrict__ out,           // [B*64]
    int B, int T)
{
    const int wave = (int)((blockIdx.x * blockDim.x + threadIdx.x) >> 6);
    if (wave >= B) return;
    const int lane = threadIdx.x & 63;

    const int start = offsets[wave];
    const int end   = (wave + 1 < B) ? offsets[wave + 1] : T;
    const int count = end - start;

    float acc = 0.0f;

    if (count <= 64) {
        // One coalesced load: lane l holds indices[start+l].
        int myidx = 0;
        if (lane < count) myidx = indices[start + lane];

        // Uniform trip count -> uniform branch; shfl src lane is uniform and
        // always < count (valid, active at load time). Loads are independent.
        #pragma unroll 5
        for (int j = 0; j < count; ++j) {
            const int idx = __shfl(myidx, j, 64);
            acc += weight[(size_t)idx * 64 + lane];
        }
    } else {
        // Generic fallback (not hit for L=50): wave-uniform index loads.
        for (int j = 0; j < count; ++j) {
            const int idx = indices[start + j];
            acc += weight[(size_t)idx * 64 + lane];
        }
    }

    const float inv = 1.0f / (float)((count > 0) ? count : 1);
    out[(size_t)wave * 64 + lane] = acc * inv;
}

extern "C" void kernel_launch(void* const* d_in, const int* in_sizes, int n_in,
                              void* d_out, int out_size, void* d_ws, size_t ws_size,
                              hipStream_t stream) {
    const int*   indices = (const int*)d_in[0];
    const int*   offsets = (const int*)d_in[1];
    const float* weight  = (const float*)d_in[2];

    const int T = in_sizes[0];
    const int B = in_sizes[1];

    const int bags_per_block = 4;   // 256 threads = 4 waves
    const int grid = (B + bags_per_block - 1) / bags_per_block;

    FreqAwareEmbedding_kernel<<<grid, 256, 0, stream>>>(
        indices, offsets, weight, (float*)d_out, B, T);
}

// Round 5
// 326.682 us; speedup vs baseline: 1.0704x; 1.0704x over previous
//
#include <hip/hip_runtime.h>

// EmbeddingBag(mean): V=1e6, D=64, B=16384, L=50.
// Best-measured structure (R3, 325.8 us total bench):
// One wave per bag; lanes = 4 sub-groups x 16 cols (float4 per lane = 256B row).
// ONE coalesced load puts the bag's <=64 indices in per-lane regs; __shfl
// (all-lanes-active, clamped src lane) distributes them so the ~13 row
// gathers per lane are mutually independent and in flight together.
//
// Evidence this is the roofline for the controllable part:
//  - R1 (dependent idx->row load chain) == R3 (independent) within 1% -> not
//    latency-bound; compulsory gather traffic ~213 MB is the bound.
//  - R4 (4B/lane + per-iter bpermute chains) regressed +24 us -> 16B/lane
//    with unrolled compile-time shfl slots is the right issue structure.
//  - Bench dur_us is dominated by a ~270 us harness reset floor (1 GB ws
//    poison + 256 MB weight restore, visible as ~154 us fillBufferAligned
//    dispatches at 82% HBM peak in rocprof).

__global__ __launch_bounds__(256) void FreqAwareEmbedding_kernel(
    const int* __restrict__ indices,    // [T]
    const int* __restrict__ offsets,    // [B]
    const float4* __restrict__ weight4, // [V*16] (V x 64 fp32 as float4)
    float4* __restrict__ out4,          // [B*16]
    int B, int T)
{
    const int wave = (int)((blockIdx.x * blockDim.x + threadIdx.x) >> 6);
    if (wave >= B) return;
    const int lane = threadIdx.x & 63;
    const int sub  = lane >> 4;   // 0..3: index slot within group of 4
    const int col  = lane & 15;   // float4 column within the 64-float row

    const int start = offsets[wave];
    const int end   = (wave + 1 < B) ? offsets[wave + 1] : T;
    const int count = end - start;

    float4 acc = make_float4(0.f, 0.f, 0.f, 0.f);

    if (count <= 64) {
        // Whole bag's indices in one coalesced load, one per lane.
        int myidx = 0;
        if (lane < count) myidx = indices[start + lane];

        #pragma unroll
        for (int t = 0; t < 16; ++t) {
            const int j  = sub + 4 * t;
            const int jj = (j < count) ? j : 0;        // valid, active src lane
            const int idx = __shfl(myidx, jj, 64);     // ALL 64 lanes active
            if (j < count) {
                const float4 v = weight4[(size_t)idx * 16 + col];
                acc.x += v.x; acc.y += v.y; acc.z += v.z; acc.w += v.w;
            }
        }
    } else {
        // Generic fallback (not hit for L=50).
        for (int j = sub; j < count; j += 4) {
            const int idx = indices[start + j];
            const float4 v = weight4[(size_t)idx * 16 + col];
            acc.x += v.x; acc.y += v.y; acc.z += v.z; acc.w += v.w;
        }
    }

    // Reduce the 4 sub-group partials: lanes l, l^16, l^32, l^48 share `col`.
    #pragma unroll
    for (int m = 16; m <= 32; m <<= 1) {
        acc.x += __shfl_xor(acc.x, m, 64);
        acc.y += __shfl_xor(acc.y, m, 64);
        acc.z += __shfl_xor(acc.z, m, 64);
        acc.w += __shfl_xor(acc.w, m, 64);
    }

    const float inv = 1.0f / (float)((count > 0) ? count : 1);
    acc.x *= inv; acc.y *= inv; acc.z *= inv; acc.w *= inv;

    if (sub == 0) {
        out4[(size_t)wave * 16 + col] = acc;
    }
}

extern "C" void kernel_launch(void* const* d_in, const int* in_sizes, int n_in,
                              void* d_out, int out_size, void* d_ws, size_t ws_size,
                              hipStream_t stream) {
    const int*   indices = (const int*)d_in[0];
    const int*   offsets = (const int*)d_in[1];
    const float* weight  = (const float*)d_in[2];

    const int T = in_sizes[0];
    const int B = in_sizes[1];

    const int bags_per_block = 4;   // 256 threads = 4 waves
    const int grid = (B + bags_per_block - 1) / bags_per_block;

    FreqAwareEmbedding_kernel<<<grid, 256, 0, stream>>>(
        indices, offsets, (const float4*)weight, (float4*)d_out, B, T);
}